// Round 2
// baseline (1227.518 us; speedup 1.0000x reference)
//
#include <hip/hip_runtime.h>
#include <hip/hip_bf16.h>
#include <math.h>

// Problem constants
#define TK 1024      // tokens
#define HD 1024      // hidden
#define NF3 3072     // shared ffn dim
#define NF2 2048     // routed ffn dim
#define NSH 8        // shared experts
#define NEX 32       // routed experts
#define KSEL 4       // top-k
#define RRK 64       // router rank

typedef short bf16x8 __attribute__((ext_vector_type(8)));
typedef float f32x4 __attribute__((ext_vector_type(4)));
typedef unsigned short u16;

// fp32 -> bf16 round-to-nearest-even (finite inputs)
__device__ __forceinline__ u16 f2b(float f){
  union{float f; unsigned u;} c; c.f=f;
  unsigned r = c.u + 0x7FFFu + ((c.u>>16)&1u);
  return (u16)(r>>16);
}

// XOR swizzle for [row][32] bf16 LDS tiles (64B rows): spreads the 16B slots so
// ds_read_b128 fragment reads (16 lanes @ stride 64B) and b128 writes are ~conflict-free.
__device__ __forceinline__ int swz(int row, int kb){
  return row*64 + (kb ^ (((row>>1)&3)<<4));
}

// ---------------- small kernels ----------------

__global__ void init_kernel(int* counts, int* cursors){
  int i = threadIdx.x;
  if (i < NEX){ counts[i]=0; cursors[i]=0; }
}

// per-token RMS scale; emit x (bf16) and xn_s = x*r*sn[s] (bf16) for all 8 shared experts
__global__ void rms_kernel(const float* __restrict__ x, const float* __restrict__ sn,
                           u16* __restrict__ xb, u16* __restrict__ xnb)
{
  const int t = blockIdx.x, tid = threadIdx.x;        // 256 threads, 4 elems each
  const float4 v = ((const float4*)(x + (size_t)t*HD))[tid];
  float ss = v.x*v.x + v.y*v.y + v.z*v.z + v.w*v.w;
  #pragma unroll
  for (int m=32;m>=1;m>>=1) ss += __shfl_xor(ss, m);
  __shared__ float red[4];
  if ((tid&63)==0) red[tid>>6]=ss;
  __syncthreads();
  const float r = rsqrtf((red[0]+red[1]+red[2]+red[3])*(1.0f/HD) + 1e-6f);
  ushort4 o; o.x=f2b(v.x); o.y=f2b(v.y); o.z=f2b(v.z); o.w=f2b(v.w);
  ((ushort4*)(xb + (size_t)t*HD))[tid] = o;
  #pragma unroll
  for (int s=0;s<NSH;s++){
    const float4 g = ((const float4*)(sn + (size_t)s*HD))[tid];
    ushort4 q;
    q.x=f2b(v.x*r*g.x); q.y=f2b(v.y*r*g.y); q.z=f2b(v.z*r*g.z); q.w=f2b(v.w*r*g.w);
    ((ushort4*)(xnb + ((size_t)s*TK + t)*HD))[tid] = q;
  }
}

// fp32 router: logits = (x@rd)@ru, top-4 (ties -> lower index), softmax, counts
__global__ void router_kernel(const float* __restrict__ x, const float* __restrict__ rd,
                              const float* __restrict__ ru,
                              int* __restrict__ sel, float* __restrict__ wts,
                              int* __restrict__ counts)
{
  const int t = blockIdx.x, l = threadIdx.x;          // 64 threads (1 wave)
  __shared__ float xl[HD];
  __shared__ float xr[RRK];
  __shared__ float lg[NEX];
  const float* xrow = x + (size_t)t*HD;
  for (int i=l;i<HD;i+=64) xl[i]=xrow[i];
  __syncthreads();
  float acc=0.f;
  for (int h=0;h<HD;h++) acc += xl[h]*rd[h*RRK + l];  // lane l = rank r, coalesced rd
  xr[l]=acc;
  __syncthreads();
  if (l < NEX){
    float a=0.f;
    for (int r=0;r<RRK;r++) a += xr[r]*ru[r*NEX + l];
    lg[l]=a;
  }
  __syncthreads();
  if (l==0){
    int   sk[KSEL]; float val[KSEL]; unsigned used=0;
    for (int k=0;k<KSEL;k++){
      float best=-1e30f; int bi=0;
      for (int e=0;e<NEX;e++){
        if (used & (1u<<e)) continue;
        if (lg[e] > best){ best=lg[e]; bi=e; }
      }
      used |= (1u<<bi); sk[k]=bi; val[k]=best;
    }
    const float m = val[0];
    float w[KSEL], s=0.f;
    for (int k=0;k<KSEL;k++){ w[k]=expf(val[k]-m); s+=w[k]; }
    for (int k=0;k<KSEL;k++){
      sel[t*KSEL+k]=sk[k]; wts[t*KSEL+k]=w[k]/s;
      atomicAdd(&counts[sk[k]], 1);
    }
  }
}

// exclusive scan of counts -> offsets; load-balance loss = var(counts, ddof=1)
__global__ void scan_loss_kernel(const int* __restrict__ counts, int* __restrict__ offsets,
                                 float* __restrict__ out_loss)
{
  if (threadIdx.x==0){
    int off=0; float var=0.f;
    for (int e=0;e<NEX;e++){
      offsets[e]=off; off+=counts[e];
      float d = (float)counts[e] - 128.0f;   // mean is exactly T*K/E = 128
      var += d*d;
    }
    out_loss[0] = var * (1.0f/31.0f);
  }
}

__global__ void scatter_kernel(const int* __restrict__ sel, const float* __restrict__ wts,
                               const int* __restrict__ offsets, int* __restrict__ cursors,
                               int* __restrict__ tok_of, float* __restrict__ wt_of)
{
  const int id = blockIdx.x*256 + threadIdx.x;        // 0..4095
  const int e = sel[id];
  const int pos = atomicAdd(&cursors[e], 1);
  const int slot = offsets[e] + pos;
  tok_of[slot] = id >> 2;
  wt_of[slot]  = wts[id];
}

// ---------------- GEMM kernels ----------------
// ffn_up: O[m][n] = silu(A@W1) * (A@W3), bf16 out. A is bf16 [.,1024]; W fp32 [1024][NDIM].
// BN=64, 4 waves as 2x2. W tiles transposed during staging via 8 k-strided dword loads/lane.
template<int BM, int NDIM, bool ROUTED>
__global__ __launch_bounds__(256) void ffn_up_kernel(
    const u16* __restrict__ Ab, const float* __restrict__ W1b, const float* __restrict__ W3b,
    u16* __restrict__ Ob,
    const int* __restrict__ counts, const int* __restrict__ offsets,
    const int* __restrict__ tok_of)
{
  const int z  = blockIdx.z;
  const int m0 = blockIdx.y * BM;
  const int n0 = blockIdx.x * 64;

  int Meff; const u16* A; const float *W1, *W3; u16* O; const int* toks=nullptr;
  if (ROUTED){
    Meff = counts[z];
    if (m0 >= Meff) return;
    const int off = offsets[z];
    A = Ab; toks = tok_of + off;
    W1 = W1b + (size_t)z*HD*NDIM;
    W3 = W3b + (size_t)z*HD*NDIM;
    O  = Ob  + (size_t)off*NDIM;
  } else {
    Meff = TK;
    A  = Ab  + (size_t)z*TK*HD;
    W1 = W1b + (size_t)z*HD*NDIM;
    W3 = W3b + (size_t)z*HD*NDIM;
    O  = Ob  + (size_t)z*TK*NDIM;
  }

  __shared__ u16 Al[BM*32];
  __shared__ u16 B1l[64*32];
  __shared__ u16 B3l[64*32];
  char* Alc=(char*)Al; char* B1c=(char*)B1l; char* B3c=(char*)B3l;

  const int tid = threadIdx.x;
  const int w = tid>>6, l = tid&63;
  const int wm = (w>>1)*(BM/2), wn = (w&1)*32;
  constexpr int FM = BM/32;

  f32x4 acc1[FM][2] = {};
  f32x4 acc3[FM][2] = {};

  for (int k0=0; k0<HD; k0+=32){
    // stage A tile [BM][32] bf16 (16B chunks)
    #pragma unroll
    for (int p=0;p<BM/64;p++){
      const int id = p*256 + tid;
      const int row = id>>2, c = id&3;
      const int mg = m0+row;
      size_t arow;
      if (ROUTED){ const int idx = (mg<Meff)?mg:0; arow = (size_t)toks[idx]*HD; }
      else arow = (size_t)mg*HD;
      const uint4 v = *(const uint4*)(A + arow + k0 + c*8);
      *(uint4*)(Alc + swz(row, c*16)) = v;
    }
    // stage W1/W3 tiles transposed -> [n][32k] bf16 (8 tasks, 2 per wave)
    #pragma unroll
    for (int q=0;q<2;q++){
      const int tt = q*4 + w;
      const float* W = (tt>=4)? W3 : W1;
      char* Bc = (tt>=4)? B3c : B1c;
      const int kg = tt&3;
      const float* src = W + (size_t)(k0 + kg*8)*NDIM + (n0 + l);
      float f[8];
      #pragma unroll
      for (int i=0;i<8;i++) f[i] = src[(size_t)i*NDIM];
      unsigned pk[4];
      #pragma unroll
      for (int i=0;i<4;i++) pk[i] = (unsigned)f2b(f[2*i]) | ((unsigned)f2b(f[2*i+1])<<16);
      *(uint4*)(Bc + swz(l, kg*16)) = make_uint4(pk[0],pk[1],pk[2],pk[3]);
    }
    __syncthreads();

    bf16x8 af[FM], b1f[2], b3f[2];
    #pragma unroll
    for (int mi=0;mi<FM;mi++)
      af[mi] = *(const bf16x8*)(Alc + swz(wm + mi*16 + (l&15), (l>>4)*16));
    #pragma unroll
    for (int ni=0;ni<2;ni++){
      b1f[ni] = *(const bf16x8*)(B1c + swz(wn + ni*16 + (l&15), (l>>4)*16));
      b3f[ni] = *(const bf16x8*)(B3c + swz(wn + ni*16 + (l&15), (l>>4)*16));
    }
    #pragma unroll
    for (int mi=0;mi<FM;mi++){
      #pragma unroll
      for (int ni=0;ni<2;ni++){
        acc1[mi][ni] = __builtin_amdgcn_mfma_f32_16x16x32_bf16(af[mi], b1f[ni], acc1[mi][ni], 0,0,0);
        acc3[mi][ni] = __builtin_amdgcn_mfma_f32_16x16x32_bf16(af[mi], b3f[ni], acc3[mi][ni], 0,0,0);
      }
    }
    __syncthreads();
  }

  // epilogue: silu(y1)*y3 -> bf16
  #pragma unroll
  for (int mi=0;mi<FM;mi++){
    #pragma unroll
    for (int ni=0;ni<2;ni++){
      #pragma unroll
      for (int r=0;r<4;r++){
        const int rl = wm + mi*16 + ((l>>4)<<2) + r;
        const int mg = m0 + rl;
        if (ROUTED && mg >= Meff) continue;
        const float v1 = acc1[mi][ni][r], v3 = acc3[mi][ni][r];
        const float h = v3 * v1 / (1.0f + expf(-v1));
        const int cl = wn + ni*16 + (l&15);
        O[(size_t)mg*NDIM + (n0+cl)] = f2b(h);
      }
    }
  }
}

// ffn_down: shared: out = x + 0.125*(H @ sw2) over K=8*3072 ; routed: out += w_slot*(G @ rw2)
template<bool ROUTED>
__global__ __launch_bounds__(256) void ffn_down_kernel(
    const u16* __restrict__ Ab, const float* __restrict__ W2b,
    float* __restrict__ out, const float* __restrict__ x,
    const int* __restrict__ counts, const int* __restrict__ offsets,
    const int* __restrict__ tok_of, const float* __restrict__ wt_of)
{
  const int z  = blockIdx.z;
  const int m0 = blockIdx.y*64;
  const int n0 = blockIdx.x*64;

  int Meff=TK, off=0;
  const float* W2 = W2b;
  const u16* A = Ab;
  if (ROUTED){
    Meff = counts[z];
    if (m0 >= Meff) return;
    off = offsets[z];
    A  = Ab  + (size_t)off*NF2;
    W2 = W2b + (size_t)z*NF2*HD;
  }

  __shared__ u16 Al[64*32];
  __shared__ u16 Bl[64*32];
  char* Alc=(char*)Al; char* Blc=(char*)Bl;

  const int tid=threadIdx.x, w=tid>>6, l=tid&63;
  const int wm=(w>>1)*32, wn=(w&1)*32;

  f32x4 acc[2][2] = {};

  const int KTOT = ROUTED ? NF2 : NSH*NF3;
  for (int k0=0;k0<KTOT;k0+=32){
    { // stage A tile [64][32] bf16
      const int row = tid>>2, c = tid&3;
      const int mg = m0+row;
      size_t aoff;
      if (ROUTED){
        const int idx = (mg<Meff)?mg:0;
        aoff = (size_t)idx*NF2 + k0 + c*8;
      } else {
        const int s = k0/NF3; const int f0 = k0 - s*NF3;
        aoff = ((size_t)s*TK + mg)*NF3 + f0 + c*8;
      }
      const uint4 v = *(const uint4*)(A + aoff);
      *(uint4*)(Alc + swz(row, c*16)) = v;
    }
    { // stage W2 tile transposed (1 task per wave)
      const int kg = w;
      const float* src = W2 + (size_t)(k0 + kg*8)*HD + (n0 + l);
      float f[8];
      #pragma unroll
      for (int i=0;i<8;i++) f[i] = src[(size_t)i*HD];
      unsigned pk[4];
      #pragma unroll
      for (int i=0;i<4;i++) pk[i] = (unsigned)f2b(f[2*i]) | ((unsigned)f2b(f[2*i+1])<<16);
      *(uint4*)(Blc + swz(l, kg*16)) = make_uint4(pk[0],pk[1],pk[2],pk[3]);
    }
    __syncthreads();

    bf16x8 af[2], bfr[2];
    #pragma unroll
    for (int mi=0;mi<2;mi++) af[mi]  = *(const bf16x8*)(Alc + swz(wm+mi*16+(l&15), (l>>4)*16));
    #pragma unroll
    for (int ni=0;ni<2;ni++) bfr[ni] = *(const bf16x8*)(Blc + swz(wn+ni*16+(l&15), (l>>4)*16));
    #pragma unroll
    for (int mi=0;mi<2;mi++){
      #pragma unroll
      for (int ni=0;ni<2;ni++)
        acc[mi][ni] = __builtin_amdgcn_mfma_f32_16x16x32_bf16(af[mi], bfr[ni], acc[mi][ni], 0,0,0);
    }
    __syncthreads();
  }

  #pragma unroll
  for (int mi=0;mi<2;mi++){
    #pragma unroll
    for (int ni=0;ni<2;ni++){
      #pragma unroll
      for (int r=0;r<4;r++){
        const int rl = wm + mi*16 + ((l>>4)<<2) + r;
        const int mg = m0+rl;
        const int cl = wn + ni*16 + (l&15);
        if (ROUTED){
          if (mg >= Meff) continue;
          const int slot = off + mg;
          const int tok  = tok_of[slot];
          const float wgt = wt_of[slot];
          atomicAdd(&out[(size_t)tok*HD + (n0+cl)], wgt*acc[mi][ni][r]);
        } else {
          const size_t oi = (size_t)mg*HD + (n0+cl);
          out[oi] = x[oi] + 0.125f*acc[mi][ni][r];
        }
      }
    }
  }
}

// ---------------- launch ----------------

extern "C" void kernel_launch(void* const* d_in, const int* in_sizes, int n_in,
                              void* d_out, int out_size, void* d_ws, size_t ws_size,
                              hipStream_t stream)
{
  const float* x   = (const float*)d_in[0];
  const float* sn  = (const float*)d_in[1];
  const float* sw1 = (const float*)d_in[2];
  const float* sw2 = (const float*)d_in[3];
  const float* sw3 = (const float*)d_in[4];
  const float* rw1 = (const float*)d_in[5];
  const float* rw2 = (const float*)d_in[6];
  const float* rw3 = (const float*)d_in[7];
  const float* rd  = (const float*)d_in[8];
  const float* ru  = (const float*)d_in[9];
  float* out = (float*)d_out;

  // workspace layout (~82.1 MB)
  char* ws = (char*)d_ws;
  u16* xb    = (u16*)(ws);                               // [1024][1024] bf16      2 MB
  u16* xnb   = (u16*)(ws + ((size_t)2<<20));             // [8][1024][1024] bf16  16 MB
  u16* Hbuf  = (u16*)(ws + ((size_t)18<<20));            // [8][1024][3072] bf16  48 MB
  u16* Gbuf  = (u16*)(ws + ((size_t)66<<20));            // [4096][2048] bf16     16 MB
  char* aux  = ws + ((size_t)82<<20);
  int*   sel    = (int*)(aux);                            // 4096 i32
  float* wts    = (float*)(aux + 16384);                  // 4096 f32
  int*   counts = (int*)(aux + 32768);                    // 32
  int*   offs   = (int*)(aux + 33024);                    // 32
  int*   curs   = (int*)(aux + 33280);                    // 32
  int*   tok_of = (int*)(aux + 34816);                    // 4096 i32
  float* wt_of  = (float*)(aux + 34816 + 16384);          // 4096 f32

  hipLaunchKernelGGL(init_kernel, dim3(1), dim3(64), 0, stream, counts, curs);
  hipLaunchKernelGGL(rms_kernel, dim3(TK), dim3(256), 0, stream, x, sn, xb, xnb);
  hipLaunchKernelGGL(router_kernel, dim3(TK), dim3(64), 0, stream, x, rd, ru, sel, wts, counts);
  hipLaunchKernelGGL(scan_loss_kernel, dim3(1), dim3(64), 0, stream, counts, offs,
                     out + (size_t)TK*HD);
  hipLaunchKernelGGL(scatter_kernel, dim3(16), dim3(256), 0, stream, sel, wts, offs, curs,
                     tok_of, wt_of);

  // shared experts up: M=1024 BM=128, N=3072 BN=64, z=s  -> Hbuf
  hipLaunchKernelGGL((ffn_up_kernel<128, NF3, false>), dim3(NF3/64, TK/128, NSH), dim3(256), 0,
                     stream, xnb, sw1, sw3, Hbuf, nullptr, nullptr, nullptr);
  // routed experts up (gathered): BM=64, N=2048, z=e -> Gbuf
  hipLaunchKernelGGL((ffn_up_kernel<64, NF2, true>), dim3(NF2/64, TK/64, NEX), dim3(256), 0,
                     stream, xb, rw1, rw3, Gbuf, counts, offs, tok_of);
  // shared down: out = x + mean_s(H@sw2)  (plain fp32 stores, full coverage)
  hipLaunchKernelGGL((ffn_down_kernel<false>), dim3(HD/64, TK/64, 1), dim3(256), 0, stream,
                     Hbuf, sw2, out, x, nullptr, nullptr, nullptr, nullptr);
  // routed down: out += w_slot * (G@rw2)  (atomicAdd, runs after shared down on stream)
  hipLaunchKernelGGL((ffn_down_kernel<true>), dim3(HD/64, TK/64, NEX), dim3(256), 0, stream,
                     Gbuf, rw2, out, x, counts, offs, tok_of, wt_of);
}

// Round 3
// 1071.361 us; speedup vs baseline: 1.1458x; 1.1458x over previous
//
#include <hip/hip_runtime.h>
#include <hip/hip_bf16.h>
#include <math.h>

// Problem constants
#define TK 1024      // tokens
#define HD 1024      // hidden
#define NF3 3072     // shared ffn dim
#define NF2 2048     // routed ffn dim
#define NSH 8        // shared experts
#define NEX 32       // routed experts
#define KSEL 4       // top-k
#define RRK 64       // router rank

typedef short bf16x8 __attribute__((ext_vector_type(8)));
typedef float f32x4 __attribute__((ext_vector_type(4)));
typedef unsigned short u16;

// fp32 -> bf16 round-to-nearest-even (finite inputs)
__device__ __forceinline__ u16 f2b(float f){
  union{float f; unsigned u;} c; c.f=f;
  unsigned r = c.u + 0x7FFFu + ((c.u>>16)&1u);
  return (u16)(r>>16);
}

// XOR swizzle for [row][64k] bf16 LDS tiles (128B rows, 8 chunks of 16B):
// chunk c -> c ^ (row&7). Conflict-free for both b128 writes and fragment reads.
__device__ __forceinline__ int swz8(int row, int c){
  return row*128 + ((c ^ (row&7))<<4);
}

// ---------------- small kernels ----------------

__global__ void init_kernel(int* counts, int* cursors){
  int i = threadIdx.x;
  if (i < NEX){ counts[i]=0; cursors[i]=0; }
}

// per-token: out=x (fp32 residual base for atomic accumulation),
// xb = bf16(x), xnb[s] = bf16(x*rms*sn[s])
__global__ void rms_kernel(const float* __restrict__ x, const float* __restrict__ sn,
                           u16* __restrict__ xb, u16* __restrict__ xnb,
                           float* __restrict__ out)
{
  const int t = blockIdx.x, tid = threadIdx.x;        // 256 threads, 4 elems each
  const float4 v = ((const float4*)(x + (size_t)t*HD))[tid];
  float ss = v.x*v.x + v.y*v.y + v.z*v.z + v.w*v.w;
  #pragma unroll
  for (int m=32;m>=1;m>>=1) ss += __shfl_xor(ss, m);
  __shared__ float red[4];
  if ((tid&63)==0) red[tid>>6]=ss;
  __syncthreads();
  const float r = rsqrtf((red[0]+red[1]+red[2]+red[3])*(1.0f/HD) + 1e-6f);
  ((float4*)(out + (size_t)t*HD))[tid] = v;
  ushort4 o; o.x=f2b(v.x); o.y=f2b(v.y); o.z=f2b(v.z); o.w=f2b(v.w);
  ((ushort4*)(xb + (size_t)t*HD))[tid] = o;
  #pragma unroll
  for (int s=0;s<NSH;s++){
    const float4 g = ((const float4*)(sn + (size_t)s*HD))[tid];
    ushort4 q;
    q.x=f2b(v.x*r*g.x); q.y=f2b(v.y*r*g.y); q.z=f2b(v.z*r*g.z); q.w=f2b(v.w*r*g.w);
    ((ushort4*)(xnb + ((size_t)s*TK + t)*HD))[tid] = q;
  }
}

// fp32 router: logits = (x@rd)@ru, top-4 (ties -> lower index), softmax, counts
__global__ void router_kernel(const float* __restrict__ x, const float* __restrict__ rd,
                              const float* __restrict__ ru,
                              int* __restrict__ sel, float* __restrict__ wts,
                              int* __restrict__ counts)
{
  const int t = blockIdx.x, l = threadIdx.x;          // 64 threads (1 wave)
  __shared__ float xl[HD];
  __shared__ float xr[RRK];
  __shared__ float lg[NEX];
  const float* xrow = x + (size_t)t*HD;
  for (int i=l;i<HD;i+=64) xl[i]=xrow[i];
  __syncthreads();
  float acc=0.f;
  for (int h=0;h<HD;h++) acc += xl[h]*rd[h*RRK + l];
  xr[l]=acc;
  __syncthreads();
  if (l < NEX){
    float a=0.f;
    for (int r=0;r<RRK;r++) a += xr[r]*ru[r*NEX + l];
    lg[l]=a;
  }
  __syncthreads();
  if (l==0){
    int   sk[KSEL]; float val[KSEL]; unsigned used=0;
    for (int k=0;k<KSEL;k++){
      float best=-1e30f; int bi=0;
      for (int e=0;e<NEX;e++){
        if (used & (1u<<e)) continue;
        if (lg[e] > best){ best=lg[e]; bi=e; }
      }
      used |= (1u<<bi); sk[k]=bi; val[k]=best;
    }
    const float m = val[0];
    float w[KSEL], s=0.f;
    for (int k=0;k<KSEL;k++){ w[k]=expf(val[k]-m); s+=w[k]; }
    for (int k=0;k<KSEL;k++){
      sel[t*KSEL+k]=sk[k]; wts[t*KSEL+k]=w[k]/s;
      atomicAdd(&counts[sk[k]], 1);
    }
  }
}

// exclusive scan of counts -> offsets; load-balance loss = var(counts, ddof=1)
__global__ void scan_loss_kernel(const int* __restrict__ counts, int* __restrict__ offsets,
                                 float* __restrict__ out_loss)
{
  if (threadIdx.x==0){
    int off=0; float var=0.f;
    for (int e=0;e<NEX;e++){
      offsets[e]=off; off+=counts[e];
      float d = (float)counts[e] - 128.0f;   // mean is exactly T*K/E = 128
      var += d*d;
    }
    out_loss[0] = var * (1.0f/31.0f);
  }
}

__global__ void scatter_kernel(const int* __restrict__ sel, const float* __restrict__ wts,
                               const int* __restrict__ offsets, int* __restrict__ cursors,
                               int* __restrict__ tok_of, float* __restrict__ wt_of)
{
  const int id = blockIdx.x*256 + threadIdx.x;        // 0..4095
  const int e = sel[id];
  const int pos = atomicAdd(&cursors[e], 1);
  const int slot = offsets[e] + pos;
  tok_of[slot] = id >> 2;
  wt_of[slot]  = wts[id];
}

// ---------------- GEMM kernels (128x128-ish tiles, BK=64, 4 waves 2x2) ----------------

// up: O[m][n] = bf16( silu(A@W1) * (A@W3) ), block = 128 rows x 64 cols of output,
// B-LDS holds 128 rows: 0-63 = W1 cols n0..n0+63, 64-127 = W3 cols n0..n0+63.
template<int NDIM, bool ROUTED>
__global__ __launch_bounds__(256, 2) void up_kernel(
    const u16* __restrict__ Ab, const float* __restrict__ W1b, const float* __restrict__ W3b,
    u16* __restrict__ Ob, const int* __restrict__ counts, const int* __restrict__ offsets,
    const int* __restrict__ tok_of)
{
  const int z  = blockIdx.z;
  const int m0 = blockIdx.y * 128;
  const int n0 = blockIdx.x * 64;

  int Meff; const u16* A; const float *W1, *W3; u16* O; const int* toks = nullptr;
  if (ROUTED){
    Meff = counts[z];
    if (m0 >= Meff) return;
    const int off = offsets[z];
    toks = tok_of + off; A = Ab;
    W1 = W1b + (size_t)z*HD*NDIM; W3 = W3b + (size_t)z*HD*NDIM;
    O  = Ob  + (size_t)off*NDIM;
  } else {
    Meff = TK;
    A  = Ab  + (size_t)z*TK*HD;
    W1 = W1b + (size_t)z*HD*NDIM; W3 = W3b + (size_t)z*HD*NDIM;
    O  = Ob  + (size_t)z*TK*NDIM;
  }

  __shared__ alignas(16) u16 Al[128*64];
  __shared__ alignas(16) u16 Bl[128*64];
  char* Alc = (char*)Al; char* Blc = (char*)Bl;

  const int tid = threadIdx.x, w = tid>>6, l = tid&63;
  const int wm = (w>>1)*64, wn = (w&1)*32;

  // A staging: 4 x uint4/thread; id = p*256+tid -> row = id>>3 (0..127), chunk = id&7
  const u16* asrc[4];
  #pragma unroll
  for (int p=0;p<4;p++){
    const int id  = p*256 + tid;
    const int row = id>>3;
    int mg = m0 + row;
    if (ROUTED) mg = toks[(mg < Meff) ? mg : (Meff-1)];
    asrc[p] = A + (size_t)mg*HD + (id&7)*8;
  }
  // B staging: row br = tid&127 (0-63 -> W1 col, 64-127 -> W3 col), khalf = tid>>7
  const int br = tid&127, bhalf = tid>>7;
  const float* bsrc = ((br<64) ? W1 : W3) + (size_t)bhalf*32*NDIM + (n0 + (br&63));

  f32x4 acc1[4][2] = {}; f32x4 acc3[4][2] = {};

  for (int k0 = 0; k0 < HD; k0 += 64){
    #pragma unroll
    for (int p=0;p<4;p++){
      const int id = p*256 + tid;
      const uint4 v = *(const uint4*)(asrc[p] + k0);
      *(uint4*)(Alc + swz8(id>>3, id&7)) = v;
    }
    {
      float f[32];
      #pragma unroll
      for (int i=0;i<32;i++) f[i] = bsrc[(size_t)i*NDIM];
      bsrc += (size_t)64*NDIM;
      #pragma unroll
      for (int j=0;j<4;j++){
        unsigned pk[4];
        #pragma unroll
        for (int q=0;q<4;q++)
          pk[q] = (unsigned)f2b(f[j*8+2*q]) | ((unsigned)f2b(f[j*8+2*q+1])<<16);
        *(uint4*)(Blc + swz8(br, bhalf*4 + j)) = make_uint4(pk[0],pk[1],pk[2],pk[3]);
      }
    }
    __syncthreads();

    #pragma unroll
    for (int kh=0;kh<2;kh++){
      bf16x8 af[4], b1[2], b3[2];
      #pragma unroll
      for (int mi=0;mi<4;mi++)
        af[mi] = *(const bf16x8*)(Alc + swz8(wm + mi*16 + (l&15), kh*4 + (l>>4)));
      #pragma unroll
      for (int ni=0;ni<2;ni++){
        b1[ni] = *(const bf16x8*)(Blc + swz8(     wn + ni*16 + (l&15), kh*4 + (l>>4)));
        b3[ni] = *(const bf16x8*)(Blc + swz8(64 + wn + ni*16 + (l&15), kh*4 + (l>>4)));
      }
      #pragma unroll
      for (int mi=0;mi<4;mi++){
        #pragma unroll
        for (int ni=0;ni<2;ni++){
          acc1[mi][ni] = __builtin_amdgcn_mfma_f32_16x16x32_bf16(af[mi], b1[ni], acc1[mi][ni], 0,0,0);
          acc3[mi][ni] = __builtin_amdgcn_mfma_f32_16x16x32_bf16(af[mi], b3[ni], acc3[mi][ni], 0,0,0);
        }
      }
    }
    __syncthreads();
  }

  #pragma unroll
  for (int mi=0;mi<4;mi++){
    #pragma unroll
    for (int ni=0;ni<2;ni++){
      #pragma unroll
      for (int r=0;r<4;r++){
        const int row = wm + mi*16 + ((l>>4)<<2) + r;
        const int mg  = m0 + row;
        if (ROUTED && mg >= Meff) continue;
        const float v1 = acc1[mi][ni][r], v3 = acc3[mi][ni][r];
        const float h = v3 * v1 / (1.0f + expf(-v1));
        O[(size_t)mg*NDIM + n0 + wn + ni*16 + (l&15)] = f2b(h);
      }
    }
  }
}

// down: 128x128 output tile. shared: atomicAdd(out, 0.125*(H_s @ sw2_s)) split over z=8 experts.
// routed: atomicAdd(out[tok], w_slot*(G @ rw2_e)), z=32 experts.
template<bool ROUTED>
__global__ __launch_bounds__(256, 2) void down_kernel(
    const u16* __restrict__ Ab, const float* __restrict__ W2b, float* __restrict__ out,
    const int* __restrict__ counts, const int* __restrict__ offsets,
    const int* __restrict__ tok_of, const float* __restrict__ wt_of)
{
  const int z  = blockIdx.z;
  const int m0 = blockIdx.y * 128;
  const int n0 = blockIdx.x * 128;
  constexpr int KT  = ROUTED ? NF2 : NF3;

  int Meff = TK, off = 0;
  const u16* A; const float* W2;
  if (ROUTED){
    Meff = counts[z];
    if (m0 >= Meff) return;
    off = offsets[z];
    A  = Ab  + (size_t)off*NF2;
    W2 = W2b + (size_t)z*NF2*HD;
  } else {
    A  = Ab  + (size_t)z*TK*NF3;
    W2 = W2b + (size_t)z*NF3*HD;
  }

  __shared__ alignas(16) u16 Al[128*64];
  __shared__ alignas(16) u16 Bl[128*64];
  char* Alc = (char*)Al; char* Blc = (char*)Bl;

  const int tid = threadIdx.x, w = tid>>6, l = tid&63;
  const int wm = (w>>1)*64, wn = (w&1)*64;

  const u16* asrc[4];
  #pragma unroll
  for (int p=0;p<4;p++){
    const int id  = p*256 + tid;
    const int row = id>>3;
    int mg = m0 + row;
    if (ROUTED && mg >= Meff) mg = Meff-1;
    asrc[p] = A + (size_t)mg*KT + (id&7)*8;
  }
  const int br = tid&127, bhalf = tid>>7;
  const float* bsrc = W2 + (size_t)bhalf*32*HD + (n0 + br);

  f32x4 acc[4][4] = {};

  for (int k0 = 0; k0 < KT; k0 += 64){
    #pragma unroll
    for (int p=0;p<4;p++){
      const int id = p*256 + tid;
      const uint4 v = *(const uint4*)(asrc[p] + k0);
      *(uint4*)(Alc + swz8(id>>3, id&7)) = v;
    }
    {
      float f[32];
      #pragma unroll
      for (int i=0;i<32;i++) f[i] = bsrc[(size_t)i*HD];
      bsrc += (size_t)64*HD;
      #pragma unroll
      for (int j=0;j<4;j++){
        unsigned pk[4];
        #pragma unroll
        for (int q=0;q<4;q++)
          pk[q] = (unsigned)f2b(f[j*8+2*q]) | ((unsigned)f2b(f[j*8+2*q+1])<<16);
        *(uint4*)(Blc + swz8(br, bhalf*4 + j)) = make_uint4(pk[0],pk[1],pk[2],pk[3]);
      }
    }
    __syncthreads();

    #pragma unroll
    for (int kh=0;kh<2;kh++){
      bf16x8 af[4], bfr[4];
      #pragma unroll
      for (int mi=0;mi<4;mi++)
        af[mi]  = *(const bf16x8*)(Alc + swz8(wm + mi*16 + (l&15), kh*4 + (l>>4)));
      #pragma unroll
      for (int ni=0;ni<4;ni++)
        bfr[ni] = *(const bf16x8*)(Blc + swz8(wn + ni*16 + (l&15), kh*4 + (l>>4)));
      #pragma unroll
      for (int mi=0;mi<4;mi++){
        #pragma unroll
        for (int ni=0;ni<4;ni++)
          acc[mi][ni] = __builtin_amdgcn_mfma_f32_16x16x32_bf16(af[mi], bfr[ni], acc[mi][ni], 0,0,0);
      }
    }
    __syncthreads();
  }

  #pragma unroll
  for (int mi=0;mi<4;mi++){
    #pragma unroll
    for (int ni=0;ni<4;ni++){
      #pragma unroll
      for (int r=0;r<4;r++){
        const int row = wm + mi*16 + ((l>>4)<<2) + r;
        const int mg  = m0 + row;
        const int col = n0 + wn + ni*16 + (l&15);
        if (ROUTED){
          if (mg >= Meff) continue;
          const int slot = off + mg;
          atomicAdd(&out[(size_t)tok_of[slot]*HD + col], wt_of[slot]*acc[mi][ni][r]);
        } else {
          atomicAdd(&out[(size_t)mg*HD + col], 0.125f*acc[mi][ni][r]);
        }
      }
    }
  }
}

// ---------------- launch ----------------

extern "C" void kernel_launch(void* const* d_in, const int* in_sizes, int n_in,
                              void* d_out, int out_size, void* d_ws, size_t ws_size,
                              hipStream_t stream)
{
  const float* x   = (const float*)d_in[0];
  const float* sn  = (const float*)d_in[1];
  const float* sw1 = (const float*)d_in[2];
  const float* sw2 = (const float*)d_in[3];
  const float* sw3 = (const float*)d_in[4];
  const float* rw1 = (const float*)d_in[5];
  const float* rw2 = (const float*)d_in[6];
  const float* rw3 = (const float*)d_in[7];
  const float* rd  = (const float*)d_in[8];
  const float* ru  = (const float*)d_in[9];
  float* out = (float*)d_out;

  // workspace layout (~82.1 MB)
  char* ws = (char*)d_ws;
  u16* xb    = (u16*)(ws);                               // [1024][1024] bf16      2 MB
  u16* xnb   = (u16*)(ws + ((size_t)2<<20));             // [8][1024][1024] bf16  16 MB
  u16* Hbuf  = (u16*)(ws + ((size_t)18<<20));            // [8][1024][3072] bf16  48 MB
  u16* Gbuf  = (u16*)(ws + ((size_t)66<<20));            // [4096][2048] bf16     16 MB
  char* aux  = ws + ((size_t)82<<20);
  int*   sel    = (int*)(aux);                            // 4096 i32
  float* wts    = (float*)(aux + 16384);                  // 4096 f32
  int*   counts = (int*)(aux + 32768);                    // 32
  int*   offs   = (int*)(aux + 33024);                    // 32
  int*   curs   = (int*)(aux + 33280);                    // 32
  int*   tok_of = (int*)(aux + 34816);                    // 4096 i32
  float* wt_of  = (float*)(aux + 34816 + 16384);          // 4096 f32

  hipLaunchKernelGGL(init_kernel, dim3(1), dim3(64), 0, stream, counts, curs);
  hipLaunchKernelGGL(rms_kernel, dim3(TK), dim3(256), 0, stream, x, sn, xb, xnb, out);
  hipLaunchKernelGGL(router_kernel, dim3(TK), dim3(64), 0, stream, x, rd, ru, sel, wts, counts);
  hipLaunchKernelGGL(scan_loss_kernel, dim3(1), dim3(64), 0, stream, counts, offs,
                     out + (size_t)TK*HD);
  hipLaunchKernelGGL(scatter_kernel, dim3(16), dim3(256), 0, stream, sel, wts, offs, curs,
                     tok_of, wt_of);

  // shared up: M=1024/128, N=3072/64, z=8 experts -> Hbuf
  hipLaunchKernelGGL((up_kernel<NF3, false>), dim3(NF3/64, TK/128, NSH), dim3(256), 0,
                     stream, xnb, sw1, sw3, Hbuf, nullptr, nullptr, nullptr);
  // routed up (gathered): N=2048/64, z=32 experts -> Gbuf
  hipLaunchKernelGGL((up_kernel<NF2, true>), dim3(NF2/64, TK/128, NEX), dim3(256), 0,
                     stream, xb, rw1, rw3, Gbuf, counts, offs, tok_of);
  // shared down: split-K over z=8 experts, atomicAdd 0.125x into out (out pre-inited to x)
  hipLaunchKernelGGL((down_kernel<false>), dim3(HD/128, TK/128, NSH), dim3(256), 0, stream,
                     Hbuf, sw2, out, nullptr, nullptr, nullptr, nullptr);
  // routed down: atomicAdd w_slot * (G @ rw2) into out
  hipLaunchKernelGGL((down_kernel<true>), dim3(HD/128, TK/128, NEX), dim3(256), 0, stream,
                     Gbuf, rw2, out, counts, offs, tok_of, wt_of);
}

// Round 4
// 1034.624 us; speedup vs baseline: 1.1864x; 1.0355x over previous
//
#include <hip/hip_runtime.h>
#include <hip/hip_bf16.h>
#include <math.h>

// Problem constants
#define TK 1024      // tokens
#define HD 1024      // hidden
#define NF3 3072     // shared ffn dim
#define NF2 2048     // routed ffn dim
#define NSH 8        // shared experts
#define NEX 32       // routed experts
#define KSEL 4       // top-k
#define RRK 64       // router rank

typedef short bf16x8 __attribute__((ext_vector_type(8)));
typedef float f32x4 __attribute__((ext_vector_type(4)));
typedef unsigned short u16;

// fp32 -> bf16 round-to-nearest-even (finite inputs)
__device__ __forceinline__ u16 f2b(float f){
  union{float f; unsigned u;} c; c.f=f;
  unsigned r = c.u + 0x7FFFu + ((c.u>>16)&1u);
  return (u16)(r>>16);
}

// pack 2 floats -> 2 bf16 in a dword (compiler emits v_cvt_pk_bf16_f32)
__device__ __forceinline__ unsigned pk2(float a, float b){
  __hip_bfloat162 h = __float22bfloat162_rn(float2{a, b});
  union{__hip_bfloat162 h; unsigned u;} c; c.h = h; return c.u;
}

// XOR swizzle for [row][64k] bf16 LDS tiles (128B rows, 8 chunks of 16B):
// chunk c -> c ^ (row&7). Conflict-free for both b128 writes and fragment reads.
__device__ __forceinline__ int swz8(int row, int c){
  return row*128 + ((c ^ (row&7))<<4);
}

// ---------------- small kernels ----------------

__global__ void init_kernel(int* counts, int* cursors){
  int i = threadIdx.x;
  if (i < NEX){ counts[i]=0; cursors[i]=0; }
}

// per-token: out=x (fp32 residual base for atomic accumulation),
// xb = bf16(x), xnb[s] = bf16(x*rms*sn[s])
__global__ void rms_kernel(const float* __restrict__ x, const float* __restrict__ sn,
                           u16* __restrict__ xb, u16* __restrict__ xnb,
                           float* __restrict__ out)
{
  const int t = blockIdx.x, tid = threadIdx.x;        // 256 threads, 4 elems each
  const float4 v = ((const float4*)(x + (size_t)t*HD))[tid];
  float ss = v.x*v.x + v.y*v.y + v.z*v.z + v.w*v.w;
  #pragma unroll
  for (int m=32;m>=1;m>>=1) ss += __shfl_xor(ss, m);
  __shared__ float red[4];
  if ((tid&63)==0) red[tid>>6]=ss;
  __syncthreads();
  const float r = rsqrtf((red[0]+red[1]+red[2]+red[3])*(1.0f/HD) + 1e-6f);
  ((float4*)(out + (size_t)t*HD))[tid] = v;
  ushort4 o; o.x=f2b(v.x); o.y=f2b(v.y); o.z=f2b(v.z); o.w=f2b(v.w);
  ((ushort4*)(xb + (size_t)t*HD))[tid] = o;
  #pragma unroll
  for (int s=0;s<NSH;s++){
    const float4 g = ((const float4*)(sn + (size_t)s*HD))[tid];
    ushort4 q;
    q.x=f2b(v.x*r*g.x); q.y=f2b(v.y*r*g.y); q.z=f2b(v.z*r*g.z); q.w=f2b(v.w*r*g.w);
    ((ushort4*)(xnb + ((size_t)s*TK + t)*HD))[tid] = q;
  }
}

// fp32 router: logits = (x@rd)@ru, top-4 (ties -> lower index), softmax, counts
__global__ void router_kernel(const float* __restrict__ x, const float* __restrict__ rd,
                              const float* __restrict__ ru,
                              int* __restrict__ sel, float* __restrict__ wts,
                              int* __restrict__ counts)
{
  const int t = blockIdx.x, l = threadIdx.x;          // 64 threads (1 wave)
  __shared__ float xl[HD];
  __shared__ float xr[RRK];
  __shared__ float lg[NEX];
  const float* xrow = x + (size_t)t*HD;
  for (int i=l;i<HD;i+=64) xl[i]=xrow[i];
  __syncthreads();
  float acc=0.f;
  for (int h=0;h<HD;h++) acc += xl[h]*rd[h*RRK + l];
  xr[l]=acc;
  __syncthreads();
  if (l < NEX){
    float a=0.f;
    for (int r=0;r<RRK;r++) a += xr[r]*ru[r*NEX + l];
    lg[l]=a;
  }
  __syncthreads();
  if (l==0){
    int   sk[KSEL]; float val[KSEL]; unsigned used=0;
    for (int k=0;k<KSEL;k++){
      float best=-1e30f; int bi=0;
      for (int e=0;e<NEX;e++){
        if (used & (1u<<e)) continue;
        if (lg[e] > best){ best=lg[e]; bi=e; }
      }
      used |= (1u<<bi); sk[k]=bi; val[k]=best;
    }
    const float m = val[0];
    float w[KSEL], s=0.f;
    for (int k=0;k<KSEL;k++){ w[k]=expf(val[k]-m); s+=w[k]; }
    for (int k=0;k<KSEL;k++){
      sel[t*KSEL+k]=sk[k]; wts[t*KSEL+k]=w[k]/s;
      atomicAdd(&counts[sk[k]], 1);
    }
  }
}

// exclusive scan of counts -> offsets; load-balance loss = var(counts, ddof=1)
__global__ void scan_loss_kernel(const int* __restrict__ counts, int* __restrict__ offsets,
                                 float* __restrict__ out_loss)
{
  if (threadIdx.x==0){
    int off=0; float var=0.f;
    for (int e=0;e<NEX;e++){
      offsets[e]=off; off+=counts[e];
      float d = (float)counts[e] - 128.0f;   // mean is exactly T*K/E = 128
      var += d*d;
    }
    out_loss[0] = var * (1.0f/31.0f);
  }
}

__global__ void scatter_kernel(const int* __restrict__ sel, const float* __restrict__ wts,
                               const int* __restrict__ offsets, int* __restrict__ cursors,
                               int* __restrict__ tok_of, float* __restrict__ wt_of)
{
  const int id = blockIdx.x*256 + threadIdx.x;        // 0..4095
  const int e = sel[id];
  const int pos = atomicAdd(&cursors[e], 1);
  const int slot = offsets[e] + pos;
  tok_of[slot] = id >> 2;
  wt_of[slot]  = wts[id];
}

// ---------------- pipelined GEMM kernels (BK=64, dbuf LDS, 4 waves 2x2) ----------------

#define LOADA(FA, KE) { _Pragma("unroll") \
  for (int p=0;p<4;p++) FA[p] = *(const uint4*)(asrc[p] + (KE)); }

#define LOADB(FB, T, LD) { const float* s_ = bsrc0 + (size_t)(T)*64*(LD); _Pragma("unroll") \
  for (int i=0;i<32;i++) FB[i] = s_[(size_t)i*(LD)]; }

#define WRITES(FA, FB, COFS) { \
  _Pragma("unroll") \
  for (int p=0;p<4;p++){ const int id_=p*256+tid; *(uint4*)(Alc+(COFS)+swz8(id_>>3,id_&7)) = FA[p]; } \
  _Pragma("unroll") \
  for (int j=0;j<4;j++){ \
    const uint4 pkv_ = make_uint4(pk2(FB[j*8+0],FB[j*8+1]),pk2(FB[j*8+2],FB[j*8+3]), \
                                  pk2(FB[j*8+4],FB[j*8+5]),pk2(FB[j*8+6],FB[j*8+7])); \
    *(uint4*)(Blc+(COFS)+swz8(br, bhalf*4+j)) = pkv_; } }

// up: O[m][n] = bf16( silu(A@W1) * (A@W3) ), block = 128 rows x 64 cols of output.
// B-LDS rows: 0-63 = W1 cols n0.., 64-127 = W3 cols n0..
template<int NDIM, bool ROUTED>
__global__ __launch_bounds__(256, 2) void up_kernel(
    const u16* __restrict__ Ab, const float* __restrict__ W1b, const float* __restrict__ W3b,
    u16* __restrict__ Ob, const int* __restrict__ counts, const int* __restrict__ offsets,
    const int* __restrict__ tok_of)
{
  const int z  = blockIdx.z;
  const int m0 = blockIdx.y * 128;
  const int n0 = blockIdx.x * 64;

  int Meff; const u16* A; const float *W1, *W3; u16* O; const int* toks = nullptr;
  if (ROUTED){
    Meff = counts[z];
    if (m0 >= Meff) return;
    const int off = offsets[z];
    toks = tok_of + off; A = Ab;
    W1 = W1b + (size_t)z*HD*NDIM; W3 = W3b + (size_t)z*HD*NDIM;
    O  = Ob  + (size_t)off*NDIM;
  } else {
    Meff = TK;
    A  = Ab  + (size_t)z*TK*HD;
    W1 = W1b + (size_t)z*HD*NDIM; W3 = W3b + (size_t)z*HD*NDIM;
    O  = Ob  + (size_t)z*TK*NDIM;
  }

  __shared__ alignas(16) u16 Al[2*128*64];   // 2 x 16KB
  __shared__ alignas(16) u16 Bl[2*128*64];   // 2 x 16KB
  char* Alc = (char*)Al; char* Blc = (char*)Bl;

  const int tid = threadIdx.x, w = tid>>6, l = tid&63;
  const int wm = (w>>1)*64, wn = (w&1)*32;

  const u16* asrc[4];
  #pragma unroll
  for (int p=0;p<4;p++){
    const int id  = p*256 + tid;
    const int row = id>>3;
    int mg = m0 + row;
    if (ROUTED) mg = toks[(mg < Meff) ? mg : (Meff-1)];
    asrc[p] = A + (size_t)mg*HD + (id&7)*8;
  }
  const int br = tid&127, bhalf = tid>>7;
  const float* bsrc0 = ((br<64) ? W1 : W3) + (size_t)bhalf*32*NDIM + (n0 + (br&63));

  f32x4 acc1[4][2] = {}; f32x4 acc3[4][2] = {};

  auto compute = [&](int cofs){
    #pragma unroll
    for (int kh=0;kh<2;kh++){
      bf16x8 af[4], b1[2], b3[2];
      #pragma unroll
      for (int mi=0;mi<4;mi++)
        af[mi] = *(const bf16x8*)(Alc + cofs + swz8(wm + mi*16 + (l&15), kh*4 + (l>>4)));
      #pragma unroll
      for (int ni=0;ni<2;ni++){
        b1[ni] = *(const bf16x8*)(Blc + cofs + swz8(     wn + ni*16 + (l&15), kh*4 + (l>>4)));
        b3[ni] = *(const bf16x8*)(Blc + cofs + swz8(64 + wn + ni*16 + (l&15), kh*4 + (l>>4)));
      }
      #pragma unroll
      for (int mi=0;mi<4;mi++){
        #pragma unroll
        for (int ni=0;ni<2;ni++){
          acc1[mi][ni] = __builtin_amdgcn_mfma_f32_16x16x32_bf16(af[mi], b1[ni], acc1[mi][ni], 0,0,0);
          acc3[mi][ni] = __builtin_amdgcn_mfma_f32_16x16x32_bf16(af[mi], b3[ni], acc3[mi][ni], 0,0,0);
        }
      }
    }
  };

  uint4 fa0[4], fa1[4]; float fb0[32], fb1[32];
  LOADA(fa0, 0); LOADB(fb0, 0, NDIM);
  constexpr int NT = HD/64;                  // 16 (even)
  for (int t=0; t<NT; t+=2){
    WRITES(fa0, fb0, 0);
    LOADA(fa1, (t+1)*64); LOADB(fb1, t+1, NDIM);
    __syncthreads();
    compute(0);
    WRITES(fa1, fb1, 16384);
    if (t+2 < NT){ LOADA(fa0, (t+2)*64); LOADB(fb0, t+2, NDIM); }
    __syncthreads();
    compute(16384);
  }

  #pragma unroll
  for (int mi=0;mi<4;mi++){
    #pragma unroll
    for (int ni=0;ni<2;ni++){
      #pragma unroll
      for (int r=0;r<4;r++){
        const int row = wm + mi*16 + ((l>>4)<<2) + r;
        const int mg  = m0 + row;
        if (ROUTED && mg >= Meff) continue;
        const float v1 = acc1[mi][ni][r], v3 = acc3[mi][ni][r];
        const float h = v3 * v1 / (1.0f + expf(-v1));
        O[(size_t)mg*NDIM + n0 + wn + ni*16 + (l&15)] = f2b(h);
      }
    }
  }
}

// down: 128x128 output tile. shared: atomicAdd(out, 0.125*(H_s @ sw2_s)) split over z=8.
// routed: atomicAdd(out[tok], w_slot*(G @ rw2_e)), z=32.
template<bool ROUTED>
__global__ __launch_bounds__(256, 2) void down_kernel(
    const u16* __restrict__ Ab, const float* __restrict__ W2b, float* __restrict__ out,
    const int* __restrict__ counts, const int* __restrict__ offsets,
    const int* __restrict__ tok_of, const float* __restrict__ wt_of)
{
  const int z  = blockIdx.z;
  const int m0 = blockIdx.y * 128;
  const int n0 = blockIdx.x * 128;
  constexpr int KT = ROUTED ? NF2 : NF3;

  int Meff = TK, off = 0;
  const u16* A; const float* W2;
  if (ROUTED){
    Meff = counts[z];
    if (m0 >= Meff) return;
    off = offsets[z];
    A  = Ab  + (size_t)off*NF2;
    W2 = W2b + (size_t)z*NF2*HD;
  } else {
    A  = Ab  + (size_t)z*TK*NF3;
    W2 = W2b + (size_t)z*NF3*HD;
  }

  __shared__ alignas(16) u16 Al[2*128*64];
  __shared__ alignas(16) u16 Bl[2*128*64];
  char* Alc = (char*)Al; char* Blc = (char*)Bl;

  const int tid = threadIdx.x, w = tid>>6, l = tid&63;
  const int wm = (w>>1)*64, wn = (w&1)*64;

  const u16* asrc[4];
  #pragma unroll
  for (int p=0;p<4;p++){
    const int id  = p*256 + tid;
    const int row = id>>3;
    int mg = m0 + row;
    if (ROUTED && mg >= Meff) mg = Meff-1;
    asrc[p] = A + (size_t)mg*KT + (id&7)*8;
  }
  const int br = tid&127, bhalf = tid>>7;
  const float* bsrc0 = W2 + (size_t)bhalf*32*HD + (n0 + br);

  f32x4 acc[4][4] = {};

  auto compute = [&](int cofs){
    #pragma unroll
    for (int kh=0;kh<2;kh++){
      bf16x8 af[4], bfr[4];
      #pragma unroll
      for (int mi=0;mi<4;mi++)
        af[mi]  = *(const bf16x8*)(Alc + cofs + swz8(wm + mi*16 + (l&15), kh*4 + (l>>4)));
      #pragma unroll
      for (int ni=0;ni<4;ni++)
        bfr[ni] = *(const bf16x8*)(Blc + cofs + swz8(wn + ni*16 + (l&15), kh*4 + (l>>4)));
      #pragma unroll
      for (int mi=0;mi<4;mi++){
        #pragma unroll
        for (int ni=0;ni<4;ni++)
          acc[mi][ni] = __builtin_amdgcn_mfma_f32_16x16x32_bf16(af[mi], bfr[ni], acc[mi][ni], 0,0,0);
      }
    }
  };

  uint4 fa0[4], fa1[4]; float fb0[32], fb1[32];
  LOADA(fa0, 0); LOADB(fb0, 0, HD);
  constexpr int NT = KT/64;                  // 48 or 32 (even)
  for (int t=0; t<NT; t+=2){
    WRITES(fa0, fb0, 0);
    LOADA(fa1, (t+1)*64); LOADB(fb1, t+1, HD);
    __syncthreads();
    compute(0);
    WRITES(fa1, fb1, 16384);
    if (t+2 < NT){ LOADA(fa0, (t+2)*64); LOADB(fb0, t+2, HD); }
    __syncthreads();
    compute(16384);
  }

  #pragma unroll
  for (int mi=0;mi<4;mi++){
    #pragma unroll
    for (int ni=0;ni<4;ni++){
      #pragma unroll
      for (int r=0;r<4;r++){
        const int row = wm + mi*16 + ((l>>4)<<2) + r;
        const int mg  = m0 + row;
        const int col = n0 + wn + ni*16 + (l&15);
        if (ROUTED){
          if (mg >= Meff) continue;
          const int slot = off + mg;
          atomicAdd(&out[(size_t)tok_of[slot]*HD + col], wt_of[slot]*acc[mi][ni][r]);
        } else {
          atomicAdd(&out[(size_t)mg*HD + col], 0.125f*acc[mi][ni][r]);
        }
      }
    }
  }
}

// ---------------- launch ----------------

extern "C" void kernel_launch(void* const* d_in, const int* in_sizes, int n_in,
                              void* d_out, int out_size, void* d_ws, size_t ws_size,
                              hipStream_t stream)
{
  const float* x   = (const float*)d_in[0];
  const float* sn  = (const float*)d_in[1];
  const float* sw1 = (const float*)d_in[2];
  const float* sw2 = (const float*)d_in[3];
  const float* sw3 = (const float*)d_in[4];
  const float* rw1 = (const float*)d_in[5];
  const float* rw2 = (const float*)d_in[6];
  const float* rw3 = (const float*)d_in[7];
  const float* rd  = (const float*)d_in[8];
  const float* ru  = (const float*)d_in[9];
  float* out = (float*)d_out;

  // workspace layout (~82.1 MB)
  char* ws = (char*)d_ws;
  u16* xb    = (u16*)(ws);                               // [1024][1024] bf16      2 MB
  u16* xnb   = (u16*)(ws + ((size_t)2<<20));             // [8][1024][1024] bf16  16 MB
  u16* Hbuf  = (u16*)(ws + ((size_t)18<<20));            // [8][1024][3072] bf16  48 MB
  u16* Gbuf  = (u16*)(ws + ((size_t)66<<20));            // [4096][2048] bf16     16 MB
  char* aux  = ws + ((size_t)82<<20);
  int*   sel    = (int*)(aux);                            // 4096 i32
  float* wts    = (float*)(aux + 16384);                  // 4096 f32
  int*   counts = (int*)(aux + 32768);                    // 32
  int*   offs   = (int*)(aux + 33024);                    // 32
  int*   curs   = (int*)(aux + 33280);                    // 32
  int*   tok_of = (int*)(aux + 34816);                    // 4096 i32
  float* wt_of  = (float*)(aux + 34816 + 16384);          // 4096 f32

  hipLaunchKernelGGL(init_kernel, dim3(1), dim3(64), 0, stream, counts, curs);
  hipLaunchKernelGGL(rms_kernel, dim3(TK), dim3(256), 0, stream, x, sn, xb, xnb, out);
  hipLaunchKernelGGL(router_kernel, dim3(TK), dim3(64), 0, stream, x, rd, ru, sel, wts, counts);
  hipLaunchKernelGGL(scan_loss_kernel, dim3(1), dim3(64), 0, stream, counts, offs,
                     out + (size_t)TK*HD);
  hipLaunchKernelGGL(scatter_kernel, dim3(16), dim3(256), 0, stream, sel, wts, offs, curs,
                     tok_of, wt_of);

  // shared up: M=1024/128, N=3072/64, z=8 experts -> Hbuf
  hipLaunchKernelGGL((up_kernel<NF3, false>), dim3(NF3/64, TK/128, NSH), dim3(256), 0,
                     stream, xnb, sw1, sw3, Hbuf, nullptr, nullptr, nullptr);
  // routed up (gathered): N=2048/64, z=32 experts -> Gbuf
  hipLaunchKernelGGL((up_kernel<NF2, true>), dim3(NF2/64, TK/128, NEX), dim3(256), 0,
                     stream, xb, rw1, rw3, Gbuf, counts, offs, tok_of);
  // shared down: split-K over z=8 experts, atomicAdd 0.125x into out (out pre-inited to x)
  hipLaunchKernelGGL((down_kernel<false>), dim3(HD/128, TK/128, NSH), dim3(256), 0, stream,
                     Hbuf, sw2, out, nullptr, nullptr, nullptr, nullptr);
  // routed down: atomicAdd w_slot * (G @ rw2) into out
  hipLaunchKernelGGL((down_kernel<true>), dim3(HD/128, TK/128, NEX), dim3(256), 0, stream,
                     Gbuf, rw2, out, counts, offs, tok_of, wt_of);
}

// Round 5
// 780.378 us; speedup vs baseline: 1.5730x; 1.3258x over previous
//
#include <hip/hip_runtime.h>
#include <hip/hip_bf16.h>
#include <math.h>

// Problem constants
#define TK 1024      // tokens
#define HD 1024      // hidden
#define NF3 3072     // shared ffn dim
#define NF2 2048     // routed ffn dim
#define NSH 8        // shared experts
#define NEX 32       // routed experts
#define KSEL 4       // top-k
#define RRK 64       // router rank

typedef short bf16x8 __attribute__((ext_vector_type(8)));
typedef float f32x4 __attribute__((ext_vector_type(4)));
typedef unsigned short u16;

// fp32 -> bf16 round-to-nearest-even (finite inputs)
__device__ __forceinline__ u16 f2b(float f){
  union{float f; unsigned u;} c; c.f=f;
  unsigned r = c.u + 0x7FFFu + ((c.u>>16)&1u);
  return (u16)(r>>16);
}

// pack 2 floats -> 2 bf16 in a dword (v_cvt_pk_bf16_f32)
__device__ __forceinline__ unsigned pk2(float a, float b){
  __hip_bfloat162 h = __float22bfloat162_rn(float2{a, b});
  union{__hip_bfloat162 h; unsigned u;} c; c.h = h; return c.u;
}

// XOR swizzle for [row][64k] bf16 LDS tiles (128B rows, 8 chunks of 16B):
// chunk c lives at slot c ^ (row&7). Conflict-free b128 reads & writes.
__device__ __forceinline__ int swz8(int row, int c){
  return row*128 + ((c ^ (row&7))<<4);
}

// async global->LDS, 16B per lane. LDS dest must be linear (base + lane*16).
#define GLDS16(gptr, lptr) \
  __builtin_amdgcn_global_load_lds((const __attribute__((address_space(1))) unsigned*)(gptr), \
                                   (__attribute__((address_space(3))) unsigned*)(lptr), 16, 0, 0)

// ---------------- small kernels ----------------

__global__ void init_kernel(int* counts, int* cursors){
  int i = threadIdx.x;
  if (i < NEX){ counts[i]=0; cursors[i]=0; }
}

// per-token: out=x (fp32 residual base for atomic accumulation),
// xb = bf16(x), xnb[s] = bf16(x*rms*sn[s])
__global__ void rms_kernel(const float* __restrict__ x, const float* __restrict__ sn,
                           u16* __restrict__ xb, u16* __restrict__ xnb,
                           float* __restrict__ out)
{
  const int t = blockIdx.x, tid = threadIdx.x;        // 256 threads, 4 elems each
  const float4 v = ((const float4*)(x + (size_t)t*HD))[tid];
  float ss = v.x*v.x + v.y*v.y + v.z*v.z + v.w*v.w;
  #pragma unroll
  for (int m=32;m>=1;m>>=1) ss += __shfl_xor(ss, m);
  __shared__ float red[4];
  if ((tid&63)==0) red[tid>>6]=ss;
  __syncthreads();
  const float r = rsqrtf((red[0]+red[1]+red[2]+red[3])*(1.0f/HD) + 1e-6f);
  ((float4*)(out + (size_t)t*HD))[tid] = v;
  ushort4 o; o.x=f2b(v.x); o.y=f2b(v.y); o.z=f2b(v.z); o.w=f2b(v.w);
  ((ushort4*)(xb + (size_t)t*HD))[tid] = o;
  #pragma unroll
  for (int s=0;s<NSH;s++){
    const float4 g = ((const float4*)(sn + (size_t)s*HD))[tid];
    ushort4 q;
    q.x=f2b(v.x*r*g.x); q.y=f2b(v.y*r*g.y); q.z=f2b(v.z*r*g.z); q.w=f2b(v.w*r*g.w);
    ((ushort4*)(xnb + ((size_t)s*TK + t)*HD))[tid] = q;
  }
}

// fp32 router: logits = (x@rd)@ru, top-4 (ties -> lower index), softmax, counts
__global__ void router_kernel(const float* __restrict__ x, const float* __restrict__ rd,
                              const float* __restrict__ ru,
                              int* __restrict__ sel, float* __restrict__ wts,
                              int* __restrict__ counts)
{
  const int t = blockIdx.x, l = threadIdx.x;          // 64 threads (1 wave)
  __shared__ float xl[HD];
  __shared__ float xr[RRK];
  __shared__ float lg[NEX];
  const float* xrow = x + (size_t)t*HD;
  for (int i=l;i<HD;i+=64) xl[i]=xrow[i];
  __syncthreads();
  float acc=0.f;
  for (int h=0;h<HD;h++) acc += xl[h]*rd[h*RRK + l];
  xr[l]=acc;
  __syncthreads();
  if (l < NEX){
    float a=0.f;
    for (int r=0;r<RRK;r++) a += xr[r]*ru[r*NEX + l];
    lg[l]=a;
  }
  __syncthreads();
  if (l==0){
    int   sk[KSEL]; float val[KSEL]; unsigned used=0;
    for (int k=0;k<KSEL;k++){
      float best=-1e30f; int bi=0;
      for (int e=0;e<NEX;e++){
        if (used & (1u<<e)) continue;
        if (lg[e] > best){ best=lg[e]; bi=e; }
      }
      used |= (1u<<bi); sk[k]=bi; val[k]=best;
    }
    const float m = val[0];
    float w[KSEL], s=0.f;
    for (int k=0;k<KSEL;k++){ w[k]=expf(val[k]-m); s+=w[k]; }
    for (int k=0;k<KSEL;k++){
      sel[t*KSEL+k]=sk[k]; wts[t*KSEL+k]=w[k]/s;
      atomicAdd(&counts[sk[k]], 1);
    }
  }
}

// exclusive scan of counts -> offsets; load-balance loss = var(counts, ddof=1)
__global__ void scan_loss_kernel(const int* __restrict__ counts, int* __restrict__ offsets,
                                 float* __restrict__ out_loss)
{
  if (threadIdx.x==0){
    int off=0; float var=0.f;
    for (int e=0;e<NEX;e++){
      offsets[e]=off; off+=counts[e];
      float d = (float)counts[e] - 128.0f;   // mean is exactly T*K/E = 128
      var += d*d;
    }
    out_loss[0] = var * (1.0f/31.0f);
  }
}

__global__ void scatter_kernel(const int* __restrict__ sel, const float* __restrict__ wts,
                               const int* __restrict__ offsets, int* __restrict__ cursors,
                               int* __restrict__ tok_of, float* __restrict__ wt_of)
{
  const int id = blockIdx.x*256 + threadIdx.x;        // 0..4095
  const int e = sel[id];
  const int pos = atomicAdd(&cursors[e], 1);
  const int slot = offsets[e] + pos;
  tok_of[slot] = id >> 2;
  wt_of[slot]  = wts[id];
}

// ---- pipelined GEMMs: A via async global_load_lds (bf16), B reg-staged fp32->bf16,
// ---- dbuf LDS, ONE barrier per K-step. 4 waves 2x2.

// up: O[m][n] = bf16( silu(A@W1) * (A@W3) ), block = 128 rows x 64 cols.
// B-LDS rows: 0-63 = W1 cols n0.., 64-127 = W3 cols n0..
template<int NDIM, bool ROUTED>
__global__ __launch_bounds__(256, 2) void up_kernel(
    const u16* __restrict__ Ab, const float* __restrict__ W1b, const float* __restrict__ W3b,
    u16* __restrict__ Ob, const int* __restrict__ counts, const int* __restrict__ offsets,
    const int* __restrict__ tok_of)
{
  const int z  = blockIdx.z;
  const int m0 = blockIdx.y * 128;
  const int n0 = blockIdx.x * 64;

  int Meff; const u16* A; const float *W1, *W3; u16* O; const int* toks = nullptr;
  if (ROUTED){
    Meff = counts[z];
    if (m0 >= Meff) return;
    const int off = offsets[z];
    toks = tok_of + off; A = Ab;
    W1 = W1b + (size_t)z*HD*NDIM; W3 = W3b + (size_t)z*HD*NDIM;
    O  = Ob  + (size_t)off*NDIM;
  } else {
    Meff = TK;
    A  = Ab  + (size_t)z*TK*HD;
    W1 = W1b + (size_t)z*HD*NDIM; W3 = W3b + (size_t)z*HD*NDIM;
    O  = Ob  + (size_t)z*TK*NDIM;
  }

  __shared__ alignas(16) u16 Al[2*128*64];   // 2 x 16KB bf16 A
  __shared__ alignas(16) u16 Bl[2*128*64];   // 2 x 16KB bf16 B
  char* Alc = (char*)Al; char* Blc = (char*)Bl;

  const int tid = threadIdx.x, w = tid>>6, l = tid&63;
  const int wm = (w>>1)*64, wn = (w&1)*32;

  // A: per-thread global src with chunk pre-swizzle; LDS dest linear (id*16)
  const u16* asrc[4];
  #pragma unroll
  for (int p=0;p<4;p++){
    const int id  = p*256 + tid;
    const int row = id>>3;
    const int chunk = (id&7) ^ (row&7);
    int mg = m0 + row;
    if (ROUTED) mg = toks[(mg < Meff) ? mg : (Meff-1)];
    asrc[p] = A + (size_t)mg*HD + chunk*8;
  }
  const int br = tid&127, bhalf = tid>>7;
  const float* bsrc0 = ((br<64) ? W1 : W3) + (size_t)bhalf*32*NDIM + (n0 + (br&63));

  f32x4 acc1[4][2] = {}; f32x4 acc3[4][2] = {};

  auto issueA = [&](int ke, int bufb){
    #pragma unroll
    for (int p=0;p<4;p++)
      GLDS16(asrc[p] + ke, Alc + bufb + ((p*256+tid)<<4));
  };
  auto loadB = [&](float* f, int t){
    const float* s_ = bsrc0 + (size_t)t*64*NDIM;
    #pragma unroll
    for (int i=0;i<32;i++) f[i] = s_[(size_t)i*NDIM];
  };
  auto writeB = [&](const float* f, int bufb){
    #pragma unroll
    for (int j=0;j<4;j++){
      const uint4 v = make_uint4(pk2(f[j*8+0],f[j*8+1]), pk2(f[j*8+2],f[j*8+3]),
                                 pk2(f[j*8+4],f[j*8+5]), pk2(f[j*8+6],f[j*8+7]));
      *(uint4*)(Blc + bufb + swz8(br, bhalf*4+j)) = v;
    }
  };
  auto compute = [&](int cofs){
    #pragma unroll
    for (int kh=0;kh<2;kh++){
      bf16x8 af[4], b1[2], b3[2];
      #pragma unroll
      for (int mi=0;mi<4;mi++)
        af[mi] = *(const bf16x8*)(Alc + cofs + swz8(wm + mi*16 + (l&15), kh*4 + (l>>4)));
      #pragma unroll
      for (int ni=0;ni<2;ni++){
        b1[ni] = *(const bf16x8*)(Blc + cofs + swz8(     wn + ni*16 + (l&15), kh*4 + (l>>4)));
        b3[ni] = *(const bf16x8*)(Blc + cofs + swz8(64 + wn + ni*16 + (l&15), kh*4 + (l>>4)));
      }
      #pragma unroll
      for (int mi=0;mi<4;mi++){
        #pragma unroll
        for (int ni=0;ni<2;ni++){
          acc1[mi][ni] = __builtin_amdgcn_mfma_f32_16x16x32_bf16(af[mi], b1[ni], acc1[mi][ni], 0,0,0);
          acc3[mi][ni] = __builtin_amdgcn_mfma_f32_16x16x32_bf16(af[mi], b3[ni], acc3[mi][ni], 0,0,0);
        }
      }
    }
  };

  float fb[32];
  issueA(0, 0); loadB(fb, 0); writeB(fb, 0);
  __syncthreads();                                // drains vmcnt (A in LDS)

  constexpr int NT = HD/64;                       // 16
  for (int t=0; t<NT; ++t){
    const int cur = (t&1)*16384, nxt = ((t+1)&1)*16384;
    if (t+1 < NT){ issueA((t+1)*64, nxt); loadB(fb, t+1); }
    compute(cur);
    if (t+1 < NT) writeB(fb, nxt);
    __syncthreads();
  }

  #pragma unroll
  for (int mi=0;mi<4;mi++){
    #pragma unroll
    for (int ni=0;ni<2;ni++){
      #pragma unroll
      for (int r=0;r<4;r++){
        const int row = wm + mi*16 + ((l>>4)<<2) + r;
        const int mg  = m0 + row;
        if (ROUTED && mg >= Meff) continue;
        const float v1 = acc1[mi][ni][r], v3 = acc3[mi][ni][r];
        const float h = v3 * v1 / (1.0f + expf(-v1));
        O[(size_t)mg*NDIM + n0 + wn + ni*16 + (l&15)] = f2b(h);
      }
    }
  }
}

// down: 128x128 output tile. shared: atomicAdd(out, 0.125*(H_s @ sw2_s)) split over z=8.
// routed: atomicAdd(out[tok], w_slot*(G @ rw2_e)), z=32.
template<bool ROUTED>
__global__ __launch_bounds__(256, 2) void down_kernel(
    const u16* __restrict__ Ab, const float* __restrict__ W2b, float* __restrict__ out,
    const int* __restrict__ counts, const int* __restrict__ offsets,
    const int* __restrict__ tok_of, const float* __restrict__ wt_of)
{
  const int z  = blockIdx.z;
  const int m0 = blockIdx.y * 128;
  const int n0 = blockIdx.x * 128;
  constexpr int KT = ROUTED ? NF2 : NF3;

  int Meff = TK, off = 0;
  const u16* A; const float* W2;
  if (ROUTED){
    Meff = counts[z];
    if (m0 >= Meff) return;
    off = offsets[z];
    A  = Ab  + (size_t)off*NF2;
    W2 = W2b + (size_t)z*NF2*HD;
  } else {
    A  = Ab  + (size_t)z*TK*NF3;
    W2 = W2b + (size_t)z*NF3*HD;
  }

  __shared__ alignas(16) u16 Al[2*128*64];
  __shared__ alignas(16) u16 Bl[2*128*64];
  char* Alc = (char*)Al; char* Blc = (char*)Bl;

  const int tid = threadIdx.x, w = tid>>6, l = tid&63;
  const int wm = (w>>1)*64, wn = (w&1)*64;

  const u16* asrc[4];
  #pragma unroll
  for (int p=0;p<4;p++){
    const int id  = p*256 + tid;
    const int row = id>>3;
    const int chunk = (id&7) ^ (row&7);
    int mg = m0 + row;
    if (ROUTED && mg >= Meff) mg = Meff-1;
    asrc[p] = A + (size_t)mg*KT + chunk*8;
  }
  const int br = tid&127, bhalf = tid>>7;
  const float* bsrc0 = W2 + (size_t)bhalf*32*HD + (n0 + br);

  f32x4 acc[4][4] = {};

  auto issueA = [&](int ke, int bufb){
    #pragma unroll
    for (int p=0;p<4;p++)
      GLDS16(asrc[p] + ke, Alc + bufb + ((p*256+tid)<<4));
  };
  auto loadB = [&](float* f, int t){
    const float* s_ = bsrc0 + (size_t)t*64*HD;
    #pragma unroll
    for (int i=0;i<32;i++) f[i] = s_[(size_t)i*HD];
  };
  auto writeB = [&](const float* f, int bufb){
    #pragma unroll
    for (int j=0;j<4;j++){
      const uint4 v = make_uint4(pk2(f[j*8+0],f[j*8+1]), pk2(f[j*8+2],f[j*8+3]),
                                 pk2(f[j*8+4],f[j*8+5]), pk2(f[j*8+6],f[j*8+7]));
      *(uint4*)(Blc + bufb + swz8(br, bhalf*4+j)) = v;
    }
  };
  auto compute = [&](int cofs){
    #pragma unroll
    for (int kh=0;kh<2;kh++){
      bf16x8 af[4], bfr[4];
      #pragma unroll
      for (int mi=0;mi<4;mi++)
        af[mi]  = *(const bf16x8*)(Alc + cofs + swz8(wm + mi*16 + (l&15), kh*4 + (l>>4)));
      #pragma unroll
      for (int ni=0;ni<4;ni++)
        bfr[ni] = *(const bf16x8*)(Blc + cofs + swz8(wn + ni*16 + (l&15), kh*4 + (l>>4)));
      #pragma unroll
      for (int mi=0;mi<4;mi++){
        #pragma unroll
        for (int ni=0;ni<4;ni++)
          acc[mi][ni] = __builtin_amdgcn_mfma_f32_16x16x32_bf16(af[mi], bfr[ni], acc[mi][ni], 0,0,0);
      }
    }
  };

  float fb[32];
  issueA(0, 0); loadB(fb, 0); writeB(fb, 0);
  __syncthreads();

  constexpr int NT = KT/64;                      // 48 or 32
  for (int t=0; t<NT; ++t){
    const int cur = (t&1)*16384, nxt = ((t+1)&1)*16384;
    if (t+1 < NT){ issueA((t+1)*64, nxt); loadB(fb, t+1); }
    compute(cur);
    if (t+1 < NT) writeB(fb, nxt);
    __syncthreads();
  }

  #pragma unroll
  for (int mi=0;mi<4;mi++){
    #pragma unroll
    for (int ni=0;ni<4;ni++){
      #pragma unroll
      for (int r=0;r<4;r++){
        const int row = wm + mi*16 + ((l>>4)<<2) + r;
        const int mg  = m0 + row;
        const int col = n0 + wn + ni*16 + (l&15);
        if (ROUTED){
          if (mg >= Meff) continue;
          const int slot = off + mg;
          atomicAdd(&out[(size_t)tok_of[slot]*HD + col], wt_of[slot]*acc[mi][ni][r]);
        } else {
          atomicAdd(&out[(size_t)mg*HD + col], 0.125f*acc[mi][ni][r]);
        }
      }
    }
  }
}

// ---------------- launch ----------------

extern "C" void kernel_launch(void* const* d_in, const int* in_sizes, int n_in,
                              void* d_out, int out_size, void* d_ws, size_t ws_size,
                              hipStream_t stream)
{
  const float* x   = (const float*)d_in[0];
  const float* sn  = (const float*)d_in[1];
  const float* sw1 = (const float*)d_in[2];
  const float* sw2 = (const float*)d_in[3];
  const float* sw3 = (const float*)d_in[4];
  const float* rw1 = (const float*)d_in[5];
  const float* rw2 = (const float*)d_in[6];
  const float* rw3 = (const float*)d_in[7];
  const float* rd  = (const float*)d_in[8];
  const float* ru  = (const float*)d_in[9];
  float* out = (float*)d_out;

  // workspace layout (~82.1 MB)
  char* ws = (char*)d_ws;
  u16* xb    = (u16*)(ws);                               // [1024][1024] bf16      2 MB
  u16* xnb   = (u16*)(ws + ((size_t)2<<20));             // [8][1024][1024] bf16  16 MB
  u16* Hbuf  = (u16*)(ws + ((size_t)18<<20));            // [8][1024][3072] bf16  48 MB
  u16* Gbuf  = (u16*)(ws + ((size_t)66<<20));            // [4096][2048] bf16     16 MB
  char* aux  = ws + ((size_t)82<<20);
  int*   sel    = (int*)(aux);                            // 4096 i32
  float* wts    = (float*)(aux + 16384);                  // 4096 f32
  int*   counts = (int*)(aux + 32768);                    // 32
  int*   offs   = (int*)(aux + 33024);                    // 32
  int*   curs   = (int*)(aux + 33280);                    // 32
  int*   tok_of = (int*)(aux + 34816);                    // 4096 i32
  float* wt_of  = (float*)(aux + 34816 + 16384);          // 4096 f32

  hipLaunchKernelGGL(init_kernel, dim3(1), dim3(64), 0, stream, counts, curs);
  hipLaunchKernelGGL(rms_kernel, dim3(TK), dim3(256), 0, stream, x, sn, xb, xnb, out);
  hipLaunchKernelGGL(router_kernel, dim3(TK), dim3(64), 0, stream, x, rd, ru, sel, wts, counts);
  hipLaunchKernelGGL(scan_loss_kernel, dim3(1), dim3(64), 0, stream, counts, offs,
                     out + (size_t)TK*HD);
  hipLaunchKernelGGL(scatter_kernel, dim3(16), dim3(256), 0, stream, sel, wts, offs, curs,
                     tok_of, wt_of);

  // shared up: M=1024/128, N=3072/64, z=8 experts -> Hbuf
  hipLaunchKernelGGL((up_kernel<NF3, false>), dim3(NF3/64, TK/128, NSH), dim3(256), 0,
                     stream, xnb, sw1, sw3, Hbuf, nullptr, nullptr, nullptr);
  // routed up (gathered): N=2048/64, z=32 experts -> Gbuf
  hipLaunchKernelGGL((up_kernel<NF2, true>), dim3(NF2/64, TK/128, NEX), dim3(256), 0,
                     stream, xb, rw1, rw3, Gbuf, counts, offs, tok_of);
  // shared down: split-K over z=8 experts, atomicAdd 0.125x into out (out pre-inited to x)
  hipLaunchKernelGGL((down_kernel<false>), dim3(HD/128, TK/128, NSH), dim3(256), 0, stream,
                     Hbuf, sw2, out, nullptr, nullptr, nullptr, nullptr);
  // routed down: atomicAdd w_slot * (G @ rw2) into out
  hipLaunchKernelGGL((down_kernel<true>), dim3(HD/128, TK/128, NEX), dim3(256), 0, stream,
                     Gbuf, rw2, out, counts, offs, tok_of, wt_of);
}